// Round 18
// baseline (166.886 us; speedup 1.0000x reference)
//
#include <hip/hip_runtime.h>
#include <math.h>

// GQA B=1 S=2048 D=128 H=32 KVH=8. d_out f32.
// Round 18: attn VERBATIM (r11/r16/r17, 118us). Q-projection store fix: the
// ~27us was 16MB of scrambled 2B scatter-stores (not loads). Q-mode now BN=128
// where the view-scramble is block-uniform (head h=blockIdx.y, rows s=k*32+bx'),
// staged through LDS [64][136] and stored as coalesced dwordx4 rows.

#define SCALE 0.08838834764831843f      // 1/sqrt(128)
#define L2_10K_64 0.20762050593045952f  // log2(10000)/64

typedef short bf16x8 __attribute__((ext_vector_type(8)));
typedef float f32x4 __attribute__((ext_vector_type(4)));
typedef int i32x4 __attribute__((ext_vector_type(4)));

__device__ __forceinline__ unsigned short f2b(float f) {
  union { float f; unsigned u; } x; x.f = f;
  return (unsigned short)((x.u + 0x7FFFu + ((x.u >> 16) & 1u)) >> 16);
}
__device__ __forceinline__ float b2f(unsigned short b) {
  union { unsigned u; float f; } x; x.u = ((unsigned)b) << 16;
  return x.f;
}
__device__ __forceinline__ void lds_dma16(void* lds, const void* g) {
  __builtin_amdgcn_global_load_lds(
      (const __attribute__((address_space(1))) unsigned int*)g,
      (__attribute__((address_space(3))) unsigned int*)lds, 16, 0, 0);
}
// load 8 consecutive f32 (32B-aligned) and round to bf16x8
__device__ __forceinline__ bf16x8 ldx8(const float* p) {
  f32x4 x0 = *(const f32x4*)p;
  f32x4 x1 = *(const f32x4*)(p + 4);
  bf16x8 a;
#pragma unroll
  for (int j = 0; j < 4; ++j) a[j] = (short)f2b(x0[j]);
#pragma unroll
  for (int j = 0; j < 4; ++j) a[4 + j] = (short)f2b(x1[j]);
  return a;
}

// ---- weight prep: LDS 64x64 tile transposes, coalesced read+write ----
__global__ __launch_bounds__(256) void prep_weights(
    const float* __restrict__ Wk, const float* __restrict__ Wv,
    const float* __restrict__ Wo, const float* __restrict__ Wq,
    const float* __restrict__ bo,
    unsigned short* __restrict__ Wkt, unsigned short* __restrict__ Wvt,
    unsigned short* __restrict__ Wot, unsigned short* __restrict__ Wq2,
    float* __restrict__ out, int big) {
  __shared__ unsigned short T[64][66];
  int b = blockIdx.x, tid = threadIdx.x;
  const float* W;
  unsigned short* D;
  int K, N, tk, tn;
  if (b < 32) {
    W = Wk; D = Wkt; K = 128; N = 1024; int ti = b;       tk = ti & 1;  tn = ti >> 1;
  } else if (b < 64) {
    W = Wv; D = Wvt; K = 128; N = 1024; int ti = b - 32;  tk = ti & 1;  tn = ti >> 1;
  } else if (b < 192) {
    W = Wo; D = Wot; K = 4096; N = 128; int ti = b - 64;  tk = ti >> 1; tn = ti & 1;
  } else if (b < 320) {
    if (!big) {
      int i0 = ((b - 192) * 256 + tid) * 16;
#pragma unroll
      for (int j = 0; j < 16; ++j) Wq2[i0 + j] = f2b(Wq[i0 + j]);
      return;
    }
    W = Wq; D = Wq2; K = 128; N = 4096; int ti = b - 192; tk = ti & 1;  tn = ti >> 1;
  } else {
    int i0 = ((b - 320) * 256 + tid) * 16;  // out = bias (attn accumulates atomically)
#pragma unroll
    for (int j = 0; j < 16; ++j) out[i0 + j] = bo[(i0 + j) & 127];
    return;
  }
  int k0 = tk * 64, n0 = tn * 64;
  int c = tid & 63, q = tid >> 6;
#pragma unroll
  for (int i = 0; i < 16; ++i) {
    int r = i * 4 + q;
    T[r][c] = f2b(W[(size_t)(k0 + r) * N + n0 + c]);
  }
  __syncthreads();
#pragma unroll
  for (int i = 0; i < 16; ++i) {
    int r = i * 4 + q;
    D[(size_t)(n0 + r) * K + k0 + c] = T[c][r];
  }
}

// ---- all projections. bx<8: K (fused RoPE, kp=(g,t,d)). [8,16): V (fused
// RoPE, vt[g][d][t], view-scramble honored). bx in [16,48): Q BN=128:
// block (bx'=bx-16, my) -> head h=my, qp rows s=k*32+bx' (k=0..63), d=0..127,
// staged via LDS and stored coalesced.
__global__ __launch_bounds__(256) void proj_all(
    const float* __restrict__ keys, const float* __restrict__ values,
    const float* __restrict__ query,
    const unsigned short* __restrict__ Wkt, const unsigned short* __restrict__ Wvt,
    const unsigned short* __restrict__ Wqt,
    const float* __restrict__ bk, const float* __restrict__ bv, const float* __restrict__ bq,
    unsigned short* __restrict__ kp, unsigned short* __restrict__ vt,
    unsigned short* __restrict__ qp) {
  __shared__ __align__(16) unsigned short T[64][136];  // Q-mode staging
  int bx = blockIdx.x, m0 = blockIdx.y * 64;
  int tid = threadIdx.x;
  int w = tid >> 6, l = tid & 63;
  int l16 = l & 15, g4 = l >> 4;
  int arow = m0 + w * 16 + l16;
  const f32x4 fz = {0.f, 0.f, 0.f, 0.f};

  if (bx >= 16) {  // ---- Q-mode: BN=128, LDS-staged coalesced stores ----
    int bxq = bx - 16;           // n0 = bxq*128; n>>7 == bxq for whole block
    int n0 = bxq * 128;
    f32x4 acc[8];
#pragma unroll
    for (int nb = 0; nb < 8; ++nb) acc[nb] = fz;
#pragma unroll
    for (int kc = 0; kc < 4; ++kc) {
      int kbase = kc * 32 + g4 * 8;
      bf16x8 a = ldx8(query + (size_t)arow * 128 + kbase);
#pragma unroll
      for (int nb = 0; nb < 8; ++nb) {
        bf16x8 b = *(const bf16x8*)(Wqt + (size_t)(n0 + nb * 16 + l16) * 128 + kbase);
        acc[nb] = __builtin_amdgcn_mfma_f32_16x16x32_bf16(a, b, acc[nb], 0, 0, 0);
      }
    }
    // write C tile to LDS: T[mi&63][d], d = nb*16+l16
#pragma unroll
    for (int nb = 0; nb < 8; ++nb) {
      float bvv = bq[n0 + nb * 16 + l16];
#pragma unroll
      for (int r = 0; r < 4; ++r)
        T[w * 16 + g4 * 4 + r][nb * 16 + l16] = f2b(acc[nb][r] + bvv);
    }
    __syncthreads();
    // coalesced stores: qp[h=my][s=k*32+bxq][0..127], one 256B row per 16 lanes
    int h = blockIdx.y;
    char* qph = (char*)(qp + (size_t)h * 262144);
    const char* Tb = (const char*)T;
#pragma unroll
    for (int i = 0; i < 4; ++i) {
      int off = i * 4096 + tid * 16;       // byte offset in the 16KB data tile
      int k = off >> 8, inrow = off & 255; // k = mi&63
      i32x4 v = *(const i32x4*)(Tb + k * 272 + inrow);
      *(i32x4*)(qph + (size_t)(k * 32 + bxq) * 256 + inrow) = v;
    }
    return;
  }

  int vmode = bx >> 3;
  int n0 = (bx & 7) * 128, tb = bx & 7;
  const float* X = vmode ? values : keys;
  const unsigned short* Wt = vmode ? Wvt : Wkt;
  const float* bias = vmode ? bv : bk;
  f32x4 acc[8];
#pragma unroll
  for (int nb = 0; nb < 8; ++nb) acc[nb] = fz;
#pragma unroll
  for (int kc = 0; kc < 4; ++kc) {
    int kbase = kc * 32 + g4 * 8;
    bf16x8 a = ldx8(X + (size_t)arow * 128 + kbase);
#pragma unroll
    for (int nb = 0; nb < 8; ++nb) {
      bf16x8 b = *(const bf16x8*)(Wt + (size_t)(n0 + nb * 16 + l16) * 128 + kbase);
      acc[nb] = __builtin_amdgcn_mfma_f32_16x16x32_bf16(a, b, acc[nb], 0, 0, 0);
    }
  }
#pragma unroll
  for (int nb = 0; nb < 4; ++nb) {
    int d2 = nb * 16 + l16;
    float invf = exp2f(-(float)d2 * L2_10K_64);
    float blo = bias[n0 + d2], bhi = bias[n0 + d2 + 64];
#pragma unroll
    for (int r = 0; r < 4; ++r) {
      int mi = m0 + w * 16 + g4 * 4 + r;
      int t = (mi & 255) * 8 + tb;
      float ang = (float)t * invf;
      float sf, cf;
      __sincosf(ang, &sf, &cf);
      float x1 = acc[nb][r] + blo;
      float x2 = acc[nb + 4][r] + bhi;
      unsigned short lo = f2b(x1 * cf - x2 * sf);
      unsigned short hi = f2b(x2 * cf + x1 * sf);
      int g = mi >> 8;
      if (vmode) {
        vt[(size_t)g * 262144 + (size_t)d2 * 2048 + t] = lo;
        vt[(size_t)g * 262144 + (size_t)(d2 + 64) * 2048 + t] = hi;
      } else {
        kp[(size_t)g * 262144 + (size_t)t * 128 + d2] = lo;
        kp[(size_t)g * 262144 + (size_t)t * 128 + d2 + 64] = hi;
      }
    }
  }
}

__global__ void ws_marker(float* __restrict__ out) {
  out[blockIdx.x * 256 + threadIdx.x] = 12345.0f;
}

// ---- attn (r11/r16/r17 VERBATIM): QBLK=128, 4 waves x 32 q-rows, KVBLK=32 ----
template <int FUSED_Q>
__global__ __launch_bounds__(256, 2) void attn_kernel(
    const float* __restrict__ X, const unsigned short* __restrict__ Wqb,
    const float* __restrict__ bq, const unsigned short* __restrict__ qp,
    const unsigned short* __restrict__ kp, const unsigned short* __restrict__ vt,
    const unsigned short* __restrict__ Wot, float* __restrict__ out) {
  __shared__ __align__(16) char smem[43008];
  int bid = blockIdx.x;
  int h = bid & 31, g = h & 7;
  int qi0 = (bid >> 5) * 128;
  int tid = threadIdx.x;
  int w = tid >> 6, l = tid & 63;
  int l16 = l & 15, g4 = l >> 4;

  const f32x4 fz = {0.f, 0.f, 0.f, 0.f};
  bf16x8 qfrag[2][4];

  if (FUSED_Q) {
    unsigned short* Uni = (unsigned short*)smem;  // [4][4096] shorts = 32KB
    int r0 = h * 64 + (qi0 >> 5);
    int col0 = tid * 16;
#pragma unroll
    for (int jp = 0; jp < 2; ++jp) {
      float acc[2][16];
#pragma unroll
      for (int j = 0; j < 2; ++j)
#pragma unroll
        for (int cc = 0; cc < 16; ++cc) acc[j][cc] = bq[col0 + cc];
      const float* xr0 = X + (size_t)(r0 + jp * 2) * 128;
      const float* xr1 = xr0 + 128;
      for (int k = 0; k < 128; ++k) {
        float x0 = xr0[k], x1 = xr1[k];
        bf16x8 w0 = *(const bf16x8*)(Wqb + (size_t)k * 4096 + col0);
        bf16x8 w1 = *(const bf16x8*)(Wqb + (size_t)k * 4096 + col0 + 8);
#pragma unroll
        for (int e = 0; e < 8; ++e) {
          float f0 = b2f((unsigned short)w0[e]), f1 = b2f((unsigned short)w1[e]);
          acc[0][e] += x0 * f0; acc[0][8 + e] += x0 * f1;
          acc[1][e] += x1 * f0; acc[1][8 + e] += x1 * f1;
        }
      }
#pragma unroll
      for (int j = 0; j < 2; ++j)
#pragma unroll
        for (int cc = 0; cc < 16; ++cc)
          Uni[(jp * 2 + j) * 4096 + col0 + cc] = f2b(acc[j][cc]);
    }
    __syncthreads();
#pragma unroll
    for (int a = 0; a < 2; ++a) {
      int srow = w * 32 + a * 16 + l16;
      int sj = srow >> 5, scol = (srow & 31) * 128;
#pragma unroll
      for (int kc = 0; kc < 4; ++kc)
        qfrag[a][kc] = *(const bf16x8*)&Uni[sj * 4096 + scol + kc * 32 + g4 * 8];
    }
    __syncthreads();
  } else {
#pragma unroll
    for (int a = 0; a < 2; ++a) {
      const unsigned short* qrow =
          qp + ((size_t)h * 2048 + qi0 + w * 32 + a * 16 + l16) * 128;
#pragma unroll
      for (int kc = 0; kc < 4; ++kc)
        qfrag[a][kc] = *(const bf16x8*)(qrow + kc * 32 + g4 * 8);
    }
  }

  const char* kg = (const char*)(kp + (size_t)g * 262144);
  const char* vg = (const char*)(vt + (size_t)g * 262144);
  unsigned short* PsW = (unsigned short*)(smem + 32768) + w * 1280;  // [32][40]

#define STAGE_K(tn, kb)                                                          \
  {                                                                              \
    _Pragma("unroll") for (int i = 0; i < 2; ++i) {                              \
      int off = w * 2048 + i * 1024 + l * 16;                                    \
      int row = off >> 8, ch = (off >> 4) & 15;                                  \
      int rch = ch ^ (row & 7);                                                  \
      lds_dma16(smem + (kb) * 8192 + w * 2048 + i * 1024,                        \
                kg + (size_t)(tn) * 8192 + (size_t)row * 256 + rch * 16);        \
    }                                                                            \
  }
#define STAGE_V(tn, vb)                                                          \
  {                                                                              \
    _Pragma("unroll") for (int i = 0; i < 2; ++i) {                              \
      int off = w * 2048 + i * 1024 + l * 16;                                    \
      int vrow = off >> 6, vcb = off & 63;                                       \
      lds_dma16(smem + 16384 + (vb) * 8192 + w * 2048 + i * 1024,                \
                vg + (size_t)vrow * 4096 + (size_t)(tn) * 64 + vcb);             \
    }                                                                            \
  }

  STAGE_K(0, 0);
  STAGE_V(0, 0);
  __syncthreads();

  f32x4 oacc[2][8];
#pragma unroll
  for (int a = 0; a < 2; ++a)
#pragma unroll
    for (int db = 0; db < 8; ++db) oacc[a][db] = fz;
  float lacc[2][4] = {{0.f, 0.f, 0.f, 0.f}, {0.f, 0.f, 0.f, 0.f}};

  int c = 0;
  for (int t = 0; t < 64; ++t) {
    if (t < 63) {
      STAGE_K(t + 1, c ^ 1);
      STAGE_V(t + 1, c ^ 1);
    }

    f32x4 sacc[2][2];
    sacc[0][0] = fz; sacc[0][1] = fz; sacc[1][0] = fz; sacc[1][1] = fz;
    __builtin_amdgcn_s_setprio(1);
#pragma unroll
    for (int kc = 0; kc < 4; ++kc) {
#pragma unroll
      for (int jb = 0; jb < 2; ++jb) {
        int krow = jb * 16 + l16;
        int rch = (kc * 4 + g4) ^ (krow & 7);
        bf16x8 bfrag = *(const bf16x8*)(smem + c * 8192 + krow * 256 + rch * 16);
        sacc[0][jb] = __builtin_amdgcn_mfma_f32_16x16x32_bf16(qfrag[0][kc], bfrag, sacc[0][jb], 0, 0, 0);
        sacc[1][jb] = __builtin_amdgcn_mfma_f32_16x16x32_bf16(qfrag[1][kc], bfrag, sacc[1][jb], 0, 0, 0);
      }
    }
    __builtin_amdgcn_s_setprio(0);
#pragma unroll
    for (int a = 0; a < 2; ++a) {
#pragma unroll
      for (int r = 0; r < 4; ++r) {
        unsigned short u0 = f2b(__expf(sacc[a][0][r] * SCALE));
        unsigned short u1 = f2b(__expf(sacc[a][1][r] * SCALE));
        lacc[a][r] += b2f(u0) + b2f(u1);
        PsW[(a * 16 + g4 * 4 + r) * 40 + l16] = u0;
        PsW[(a * 16 + g4 * 4 + r) * 40 + 16 + l16] = u1;
      }
    }
    bf16x8 pfrag0 = *(const bf16x8*)(PsW + (l16)*40 + g4 * 8);
    bf16x8 pfrag1 = *(const bf16x8*)(PsW + (16 + l16) * 40 + g4 * 8);
    __builtin_amdgcn_s_setprio(1);
#pragma unroll
    for (int db = 0; db < 8; ++db) {
      bf16x8 vfrag = *(const bf16x8*)(smem + 16384 + c * 8192 + (db * 16 + l16) * 64 + g4 * 16);
      oacc[0][db] = __builtin_amdgcn_mfma_f32_16x16x32_bf16(pfrag0, vfrag, oacc[0][db], 0, 0, 0);
      oacc[1][db] = __builtin_amdgcn_mfma_f32_16x16x32_bf16(pfrag1, vfrag, oacc[1][db], 0, 0, 0);
    }
    __builtin_amdgcn_s_setprio(0);
    __syncthreads();
    c ^= 1;
  }

  float invl[2][4];
#pragma unroll
  for (int a = 0; a < 2; ++a)
#pragma unroll
    for (int r = 0; r < 4; ++r) {
      float v = lacc[a][r];
#pragma unroll
      for (int off = 1; off < 16; off <<= 1) v += __shfl_xor(v, off, 64);
      invl[a][r] = 1.f / v;
    }

  unsigned short* Otile = (unsigned short*)smem;
#pragma unroll
  for (int a = 0; a < 2; ++a)
#pragma unroll
    for (int db = 0; db < 8; ++db)
#pragma unroll
      for (int r = 0; r < 4; ++r)
        Otile[(w * 32 + a * 16 + g4 * 4 + r) * 136 + db * 16 + l16] =
            f2b(oacc[a][db][r] * invl[a][r]);
  __syncthreads();
  bf16x8 a2[2][4];
#pragma unroll
  for (int a = 0; a < 2; ++a)
#pragma unroll
    for (int kc = 0; kc < 4; ++kc)
      a2[a][kc] = *(const bf16x8*)&Otile[(w * 32 + a * 16 + l16) * 136 + kc * 32 + g4 * 8];
  f32x4 acc2[2][8];
#pragma unroll
  for (int a = 0; a < 2; ++a)
#pragma unroll
    for (int nb = 0; nb < 8; ++nb) acc2[a][nb] = fz;
#pragma unroll
  for (int kc = 0; kc < 4; ++kc) {
#pragma unroll
    for (int nb = 0; nb < 8; ++nb) {
      bf16x8 b2v = *(const bf16x8*)(Wot + (size_t)(nb * 16 + l16) * 4096 + h * 128 + kc * 32 + g4 * 8);
      acc2[0][nb] = __builtin_amdgcn_mfma_f32_16x16x32_bf16(a2[0][kc], b2v, acc2[0][nb], 0, 0, 0);
      acc2[1][nb] = __builtin_amdgcn_mfma_f32_16x16x32_bf16(a2[1][kc], b2v, acc2[1][nb], 0, 0, 0);
    }
  }
#pragma unroll
  for (int a = 0; a < 2; ++a)
#pragma unroll
    for (int nb = 0; nb < 8; ++nb)
#pragma unroll
      for (int r = 0; r < 4; ++r)
        atomicAdd(&out[(size_t)(qi0 + w * 32 + a * 16 + g4 * 4 + r) * 128 + nb * 16 + l16],
                  acc2[a][nb][r]);
#undef STAGE_K
#undef STAGE_V
}

extern "C" void kernel_launch(void* const* d_in, const int* in_sizes, int n_in,
                              void* d_out, int out_size, void* d_ws, size_t ws_size,
                              hipStream_t stream) {
  const float* query  = (const float*)d_in[0];
  const float* keys   = (const float*)d_in[1];
  const float* values = (const float*)d_in[2];
  const float* Wq = (const float*)d_in[3];
  const float* bq = (const float*)d_in[4];
  const float* Wk = (const float*)d_in[5];
  const float* bk = (const float*)d_in[6];
  const float* Wv = (const float*)d_in[7];
  const float* bv = (const float*)d_in[8];
  const float* Wo = (const float*)d_in[9];
  const float* bo = (const float*)d_in[10];
  float* out = (float*)d_out;
  char* ws = (char*)d_ws;
  const size_t MB = 1024 * 1024;
  if (ws_size < 10 * MB + 512 * 1024) {  // sentinel: absmax 12345 => ws too small
    ws_marker<<<1024, 256, 0, stream>>>(out);
    return;
  }
  unsigned short* Wq2   = (unsigned short*)(ws);                        // 1 MiB
  unsigned short* Wkt   = (unsigned short*)(ws + 1 * MB);               // 256 KiB
  unsigned short* Wvt   = (unsigned short*)(ws + 1 * MB + 256 * 1024);  // 256 KiB
  unsigned short* Wot   = (unsigned short*)(ws + 1 * MB + 512 * 1024);  // 1 MiB
  unsigned short* kproj = (unsigned short*)(ws + 2 * MB + 512 * 1024);  // 4 MiB
  unsigned short* vt    = (unsigned short*)(ws + 6 * MB + 512 * 1024);  // 4 MiB -> 10.5
  unsigned short* qproj = (unsigned short*)(ws + 10 * MB + 512 * 1024); // 16 MiB (big)
  int big = ws_size >= 27 * MB;

  prep_weights<<<384, 256, 0, stream>>>(Wk, Wv, Wo, Wq, bo, Wkt, Wvt, Wot, Wq2, out, big);

  if (big) {
    proj_all<<<dim3(48, 32), 256, 0, stream>>>(keys, values, query, Wkt, Wvt, Wq2,
                                               bk, bv, bq, kproj, vt, qproj);
    attn_kernel<0><<<512, 256, 0, stream>>>(query, Wq2, bq, qproj, kproj, vt, Wot, out);
  } else {
    proj_all<<<dim3(16, 32), 256, 0, stream>>>(keys, values, query, Wkt, Wvt, Wq2,
                                               bk, bv, bq, kproj, vt, qproj);
    attn_kernel<1><<<512, 256, 0, stream>>>(query, Wq2, bq, nullptr, kproj, vt, Wot, out);
  }
}